// Round 10
// baseline (680.824 us; speedup 1.0000x reference)
//
#include <hip/hip_runtime.h>
#include <hip/hip_bf16.h>

typedef unsigned short u16;
typedef unsigned int u32;
typedef unsigned long long u64;
typedef __attribute__((ext_vector_type(8))) short short8;
typedef __attribute__((ext_vector_type(4))) float f32x4;

#define NB 32      // trees
#define NN 128     // nodes per tree
#define HH 300     // hidden
#define G4 1200    // 4*H
#define NV 32000   // vocab
#define INW 350    // RD+E
#define KP 320     // padded K for MFMA; hb16 row stride

// scan decomposition: 32 trees x 10 slice-blocks, level-synchronous per tree
#define NSLICE 10   // 10 slices x 30 units
#define UPS 30      // hidden units per slice -> 120 gate rows
#define NROW 120
#define TPB 512
#define GMAX 16     // max nodes per MV pass
#define PRW 484     // padded pr row stride

#define SCANB (NB * NSLICE)   // 320 scan blocks
#define GEMMB 4000            // 32 mblk x 125 nblk (128x256 tiles)

// shared memory overlay (scan needs ~65.8 KB, gemm 30.7 KB)
#define SM_PH 0
#define SM_PR 19200
#define SM_CL 50176
#define SM_NID 65656
#define SM_PAR 65720
#define SM_BYTES 65792

#define A_LD(p)     __hip_atomic_load((p), __ATOMIC_RELAXED, __HIP_MEMORY_SCOPE_AGENT)
#define A_ST(p, v)  __hip_atomic_store((p), (v), __ATOMIC_RELAXED, __HIP_MEMORY_SCOPE_AGENT)
#define A_ADD(p, v) __hip_atomic_fetch_add((p), (v), __ATOMIC_RELAXED, __HIP_MEMORY_SCOPE_AGENT)

__device__ __forceinline__ float sigm(float x) { return 1.f / (1.f + __expf(-x)); }
__device__ __forceinline__ float tanh_f(float x) {
    float e = __expf(2.f * x);
    return 1.f - 2.f / (e + 1.f);
}
__device__ __forceinline__ float bf2f(u16 v) {
    u32 u = ((u32)v) << 16;
    return __uint_as_float(u);
}
__device__ __forceinline__ u16 f2bf(float f) {
    __hip_bfloat16 b = __float2bfloat16(f);
    return *reinterpret_cast<u16*>(&b);
}

// hb16: [B][129][320] bf16, slot 0 = root h; lvl_done/tree_done zeroed
__global__ void k_init(const float* __restrict__ rh, u16* __restrict__ hb16,
                       int* __restrict__ lvl_done, int* __restrict__ tree_done) {
    const int stride = gridDim.x * blockDim.x;
    const int idx = blockIdx.x * blockDim.x + threadIdx.x;
    for (int e = idx; e < NB * 129 * 20; e += stride) {
        int row = e / 20, c = 300 + (e - row * 20);
        hb16[(size_t)row * KP + c] = 0;
    }
    for (int e = idx; e < NB * HH; e += stride) {
        int b = e / HH, u = e - b * HH;
        hb16[(size_t)(b * 129) * KP + u] = f2bf(rh[e]);
    }
    for (int e = idx; e < NB * NN; e += stride) lvl_done[e] = 0;
    if (idx < NB) tree_done[idx] = 0;
}

// WihT [350][1200]; Wpack[slice][i<75][t<480] = W_hh[row(s,t)][(t/120)*75+i]
__global__ void k_pack(const float* __restrict__ W_ih, const float* __restrict__ W_hh,
                       float* __restrict__ WihT, float* __restrict__ Wpack) {
    const int tot = INW * G4 + NSLICE * 75 * 480;
    for (int n = blockIdx.x * blockDim.x + threadIdx.x; n < tot; n += gridDim.x * blockDim.x) {
        if (n < INW * G4) {
            int c = n / G4, r = n - c * G4;
            WihT[n] = W_ih[r * INW + c];
        } else {
            int m = n - INW * G4;
            int s = m / (75 * 480);
            int rem = m - s * (75 * 480);
            int i = rem / 480, t = rem - i * 480;
            int rl = t % NROW, cc = t / NROW;
            int row = 300 * (rl / UPS) + UPS * s + (rl % UPS);
            int col = cc * 75 + i;
            Wpack[m] = W_hh[row * HH + col];
        }
    }
}

// xg[node][1200] = concat(rel_emb[rel], emb[word]) @ W_ih^T + b_ih
__global__ __launch_bounds__(256) void k_xg(const int* __restrict__ relations,
                                            const int* __restrict__ prev_words,
                                            const float* __restrict__ rel_emb,
                                            const float* __restrict__ emb,
                                            const float* __restrict__ WihT,
                                            const float* __restrict__ b_ih,
                                            float* __restrict__ xg) {
    __shared__ float xl[8][INW];
    __shared__ int rid[8], wid[8];
    const int tid = threadIdx.x;
    const int nb = blockIdx.x * 8;
    if (tid < 8) { rid[tid] = relations[nb + tid]; wid[tid] = prev_words[nb + tid]; }
    __syncthreads();
    for (int idx = tid; idx < 8 * INW; idx += 256) {
        int g = idx / INW, c = idx - g * INW;
        xl[g][c] = (c < 50) ? rel_emb[rid[g] * 50 + c] : emb[wid[g] * HH + (c - 50)];
    }
    __syncthreads();
    for (int k = 0; k < 5; ++k) {
        int r = k * 256 + tid;
        if (r >= G4) break;
        float acc[8] = {0.f, 0.f, 0.f, 0.f, 0.f, 0.f, 0.f, 0.f};
        for (int c = 0; c < INW; ++c) {
            float wv = WihT[(size_t)c * G4 + r];
#pragma unroll
            for (int g = 0; g < 8; ++g) acc[g] += wv * xl[g][c];
        }
        float bi = b_ih[r];
#pragma unroll
        for (int g = 0; g < 8; ++g) xg[(size_t)(nb + g) * G4 + r] = acc[g] + bi;
    }
}

// per-tree level schedule
__global__ void k_prep(const int* __restrict__ parents, int* __restrict__ lvl_nodes,
                       int* __restrict__ lvl_cnt, int* __restrict__ lvl_start,
                       int* __restrict__ nlev) {
    __shared__ int dep[NB][NN];
    __shared__ int cnt[NB][NN];
    __shared__ int st[NB][NN];
    const int t = threadIdx.x;
    if (t < NB) {
        for (int l = 0; l < NN; ++l) cnt[t][l] = 0;
        int md = 0;
        for (int i = 0; i < NN; ++i) {
            int p = parents[t * NN + i];
            int d = (p < 0) ? 0 : dep[t][p] + 1;
            dep[t][i] = d;
            cnt[t][d]++;
            md = max(md, d);
        }
        nlev[t] = md + 1;
        int run = 0;
        for (int l = 0; l < NN; ++l) {
            st[t][l] = run;
            lvl_start[t * NN + l] = run;
            lvl_cnt[t * NN + l] = cnt[t][l];
            run += cnt[t][l];
        }
        for (int i = 0; i < NN; ++i) {
            int d = dep[t][i];
            lvl_nodes[t * NN + st[t][d]] = i;
            st[t][d]++;
        }
    }
}

// cast W_out -> bf16 [32000][320] (zero-padded K)
__global__ void k_cast_B(const float* __restrict__ W_out, u16* __restrict__ Bm) {
    for (int e = blockIdx.x * blockDim.x + threadIdx.x; e < NV * KP;
         e += gridDim.x * blockDim.x) {
        int v = e / KP, k = e - v * KP;
        float x = (k < HH) ? W_out[v * HH + k] : 0.f;
        Bm[e] = f2bf(x);
    }
}

// MV + cell for one pow2 batch of G nodes (scan path helper)
template <int G>
__device__ __forceinline__ void mv_cell(const float (&w)[75], int t, int s, int b,
                                        const int* __restrict__ nid_s,
                                        const int* __restrict__ par_s,
                                        const float* __restrict__ xg,
                                        const float* __restrict__ b_hh,
                                        u16* __restrict__ hb16,
                                        const float* __restrict__ ph,
                                        float* __restrict__ pr,
                                        float* __restrict__ c_lds) {
    if (t < 480) {
        float acc[G];
#pragma unroll
        for (int j = 0; j < G; ++j) acc[j] = 0.f;
        const int cb = (t / NROW) * 75;
#pragma unroll
        for (int i = 0; i < 75; ++i) {
            const float wv = w[i];
            const float* pp = &ph[(cb + i) * GMAX];
            if constexpr (G >= 4) {
#pragma unroll
                for (int j4 = 0; j4 < G; j4 += 4) {
                    f32x4 a = *(const f32x4*)&pp[j4];
                    acc[j4 + 0] = fmaf(wv, a[0], acc[j4 + 0]);
                    acc[j4 + 1] = fmaf(wv, a[1], acc[j4 + 1]);
                    acc[j4 + 2] = fmaf(wv, a[2], acc[j4 + 2]);
                    acc[j4 + 3] = fmaf(wv, a[3], acc[j4 + 3]);
                }
            } else {
#pragma unroll
                for (int j = 0; j < G; ++j) acc[j] = fmaf(wv, pp[j], acc[j]);
            }
        }
#pragma unroll
        for (int j = 0; j < G; ++j) pr[j * PRW + t] = acc[j];
    }
    __syncthreads();
    if (t < 15 * G) {
        const int j = t / 15, up = t - j * 15;
        const int ul0 = up * 2;
        const int i = nid_s[j];
        const int par = par_s[j];
        const int u0 = s * UPS + ul0;
        const float* pj = pr + j * PRW;
        const float* xgp = xg + (size_t)(b * NN + i) * G4;
        float cv[2], hv[2];
#pragma unroll
        for (int un = 0; un < 2; ++un) {
            const int ul = ul0 + un, u = u0 + un;
            float gs[4];
#pragma unroll
            for (int g = 0; g < 4; ++g) {
                const int rr = g * UPS + ul;
                float sum = pj[rr] + pj[NROW + rr] + pj[2 * NROW + rr] + pj[3 * NROW + rr];
                gs[g] = sum + xgp[g * HH + u] + b_hh[g * HH + u];
            }
            const float pc = c_lds[(par + 1) * UPS + ul];
            cv[un] = sigm(gs[1]) * pc + sigm(gs[0]) * tanh_f(gs[2]);
            hv[un] = sigm(gs[3]) * tanh_f(cv[un]);
        }
        c_lds[(i + 1) * UPS + ul0] = cv[0];
        c_lds[(i + 1) * UPS + ul0 + 1] = cv[1];
        u32 hp = (u32)f2bf(hv[0]) | ((u32)f2bf(hv[1]) << 16);
        A_ST((u32*)(hb16 + (size_t)(b * 129 + i + 1) * KP + u0), hp);
    }
}

// Fused scan + gated GEMM.
// Blocks 0..319: level-synchronous per-tree scan (R9 structure, proven protocol).
// Blocks 320..4319: 128x256 GEMM tiles, each gated on tree_done[mblk]==NSLICE.
// Deadlock-free: scan ids lowest -> dispatched first, contiguous per-tree groups;
// gemm blocks only occupy slots freed by retired scan blocks and poll trees that
// the (independent) scan will complete.
__global__ __launch_bounds__(TPB) void k_fused(const int* __restrict__ parents,
                                               const float* __restrict__ Wpack,
                                               const float* __restrict__ xg,
                                               const float* __restrict__ b_hh,
                                               const float* __restrict__ rh,
                                               u16* __restrict__ hb16,
                                               const int* __restrict__ lvl_nodes,
                                               const int* __restrict__ lvl_cnt,
                                               const int* __restrict__ lvl_start,
                                               const int* __restrict__ nlev,
                                               int* __restrict__ lvl_done,
                                               int* __restrict__ tree_done,
                                               const u16* __restrict__ Bbf,
                                               const float* __restrict__ b_out,
                                               float* __restrict__ out) {
    __shared__ __align__(16) char smem[SM_BYTES];
    const int t = threadIdx.x;

    if (blockIdx.x < SCANB) {
        // ---------------- scan path ----------------
        float* ph = (float*)(smem + SM_PH);
        float* pr = (float*)(smem + SM_PR);
        float* c_lds = (float*)(smem + SM_CL);
        int* nid_s = (int*)(smem + SM_NID);
        int* par_s = (int*)(smem + SM_PAR);

        const int b = blockIdx.x / NSLICE;
        const int s = blockIdx.x % NSLICE;

        float w[75];
        if (t < 480) {
            const float* wp = Wpack + (size_t)s * 75 * 480 + t;
#pragma unroll
            for (int i = 0; i < 75; ++i) w[i] = wp[i * 480];
        }
        if (t < UPS) c_lds[t] = rh[b * HH + s * UPS + t];

        const int nl = nlev[b];
        for (int l = 0; l < nl; ++l) {
            const int cnt = lvl_cnt[b * NN + l];
            const int start = lvl_start[b * NN + l];
            int off = 0;
            while (off < cnt) {
                const int rem = cnt - off;
                const int g = rem >= 16 ? 16 : rem >= 8 ? 8 : rem >= 4 ? 4 : rem >= 2 ? 2 : 1;
                if (t < g) {
                    int i = lvl_nodes[b * NN + start + off + t];
                    nid_s[t] = i;
                    par_s[t] = parents[b * NN + i];
                }
                __syncthreads();
                const int tot = g * 80;
                for (int e = t; e < tot; e += TPB) {
                    const int wqlo = e & 3, rest = e >> 2;
                    const int j = rest % g, wq4 = rest / g;
                    const int wq = wq4 * 4 + wqlo;
                    if (wq < 75) {
                        const u64* hrow = (const u64*)(hb16 +
                            (size_t)(b * 129 + par_s[j] + 1) * KP);
                        u64 v = A_LD(&hrow[wq]);
                        const int c0 = wq * 4;
                        ph[(c0 + 0) * GMAX + j] = bf2f((u16)v);
                        ph[(c0 + 1) * GMAX + j] = bf2f((u16)(v >> 16));
                        ph[(c0 + 2) * GMAX + j] = bf2f((u16)(v >> 32));
                        ph[(c0 + 3) * GMAX + j] = bf2f((u16)(v >> 48));
                    }
                }
                __syncthreads();
                switch (g) {
                    case 16: mv_cell<16>(w, t, s, b, nid_s, par_s, xg, b_hh, hb16, ph, pr, c_lds); break;
                    case 8:  mv_cell<8>(w, t, s, b, nid_s, par_s, xg, b_hh, hb16, ph, pr, c_lds); break;
                    case 4:  mv_cell<4>(w, t, s, b, nid_s, par_s, xg, b_hh, hb16, ph, pr, c_lds); break;
                    case 2:  mv_cell<2>(w, t, s, b, nid_s, par_s, xg, b_hh, hb16, ph, pr, c_lds); break;
                    default: mv_cell<1>(w, t, s, b, nid_s, par_s, xg, b_hh, hb16, ph, pr, c_lds); break;
                }
                __syncthreads();  // drains h publishes (vmcnt0) + LDS reuse safety
                off += g;
            }
            if (l + 1 < nl) {
                if (t == 0) {
                    int* dp = &lvl_done[b * NN + l];
                    const int old = A_ADD(dp, 1);
                    if (old != NSLICE - 1) {
                        while (A_LD(dp) < NSLICE) __builtin_amdgcn_s_sleep(1);
                    }
                }
                __syncthreads();
            }
        }
        // all this block's h stores drained by the loop's final barrier
        if (t == 0) A_ADD(&tree_done[b], 1);
    } else {
        // ---------------- gemm path (gated per tree) ----------------
        u16* As = (u16*)smem;                  // 128 x 40
        u16* Bs = (u16*)(smem + 10240);        // 256 x 40
        const int gid = blockIdx.x - SCANB;    // 0..3999
        const int newbid = (gid & 7) * 500 + (gid >> 3);  // XCD-chunked, bijective
        const int mblk = newbid & 31;
        const int nblk = newbid >> 5;          // 0..124
        if (t == 0) {
            while (A_LD(&tree_done[mblk]) < NSLICE) __builtin_amdgcn_s_sleep(16);
        }
        __syncthreads();
        const int lane = t & 63, wv = t >> 6;
        const int wm = wv >> 2, wn = wv & 3;   // 2x4 waves of 64x64
        const u16* Ag = hb16 + ((size_t)mblk * 129 + 1) * KP;
        const u16* Bg = Bbf + (size_t)nblk * 256 * KP;
        f32x4 acc[4][4] = {};
        const int lrow = lane & 15, lseg = lane >> 4;
        for (int kk = 0; kk < KP; kk += 32) {
            {
                int r = t >> 2, seg = t & 3;
                *(uint4*)&As[r * 40 + seg * 8] = *(const uint4*)&Ag[(size_t)r * KP + kk + seg * 8];
            }
#pragma unroll
            for (int q = 0; q < 2; ++q) {
                int sI = t + q * 512;
                int r = sI >> 2, seg = sI & 3;
                *(uint4*)&Bs[r * 40 + seg * 8] = *(const uint4*)&Bg[(size_t)r * KP + kk + seg * 8];
            }
            __syncthreads();
            short8 av[4], bv[4];
#pragma unroll
            for (int i = 0; i < 4; ++i) {
                av[i] = *(const short8*)&As[(wm * 64 + i * 16 + lrow) * 40 + lseg * 8];
                bv[i] = *(const short8*)&Bs[(wn * 64 + i * 16 + lrow) * 40 + lseg * 8];
            }
#pragma unroll
            for (int i = 0; i < 4; ++i)
#pragma unroll
                for (int j = 0; j < 4; ++j)
                    acc[i][j] = __builtin_amdgcn_mfma_f32_16x16x32_bf16(av[i], bv[j], acc[i][j],
                                                                        0, 0, 0);
            __syncthreads();
        }
#pragma unroll
        for (int j = 0; j < 4; ++j) {
            int col = nblk * 256 + wn * 64 + j * 16 + lrow;
            float bo = b_out[col];
#pragma unroll
            for (int i = 0; i < 4; ++i) {
                int row0 = mblk * 128 + wm * 64 + i * 16 + lseg * 4;
#pragma unroll
                for (int q = 0; q < 4; ++q) {
                    out[(size_t)(row0 + q) * NV + col] = acc[i][j][q] + bo;
                }
            }
        }
    }
}

extern "C" void kernel_launch(void* const* d_in, const int* in_sizes, int n_in,
                              void* d_out, int out_size, void* d_ws, size_t ws_size,
                              hipStream_t stream) {
    const float* root_hidden = (const float*)d_in[0];
    const int* relations = (const int*)d_in[1];
    const int* prev_words = (const int*)d_in[2];
    const int* parents = (const int*)d_in[3];
    const float* emb = (const float*)d_in[4];
    const float* rel_emb = (const float*)d_in[5];
    const float* W_ih = (const float*)d_in[6];
    const float* W_hh = (const float*)d_in[7];
    const float* b_ih = (const float*)d_in[8];
    const float* b_hh = (const float*)d_in[9];
    const float* W_out = (const float*)d_in[10];
    const float* b_out = (const float*)d_in[11];
    float* out = (float*)d_out;

    float* WihT = (float*)d_ws;                  // 420000 f32
    float* Wpack = WihT + 420000;                // 360000 f32
    float* xg = Wpack + 360000;                  // 4915200 f32
    u16* hb16 = (u16*)(xg + 4915200);            // 32*129*320 = 1320960 u16
    u16* Bbf = hb16 + 1320960;                   // 10240000 u16
    int* lvl_nodes = (int*)(Bbf + 10240000);     // 4096 i32
    int* lvl_cnt = lvl_nodes + 4096;             // 4096 i32
    int* lvl_start = lvl_cnt + 4096;             // 4096 i32
    int* nlev = lvl_start + 4096;                // 32 i32 (+pad)
    int* lvl_done = nlev + 64;                   // 4096 i32
    int* tree_done = lvl_done + 4096;            // 32 i32

    k_init<<<128, 256, 0, stream>>>(root_hidden, hb16, lvl_done, tree_done);
    k_pack<<<2048, 256, 0, stream>>>(W_ih, W_hh, WihT, Wpack);
    k_xg<<<NB * NN / 8, 256, 0, stream>>>(relations, prev_words, rel_emb, emb, WihT, b_ih, xg);
    k_prep<<<1, 64, 0, stream>>>(parents, lvl_nodes, lvl_cnt, lvl_start, nlev);
    k_cast_B<<<4096, 256, 0, stream>>>(W_out, Bbf);

    k_fused<<<dim3(SCANB + GEMMB), dim3(TPB), 0, stream>>>(
        parents, Wpack, xg, b_hh, root_hidden, hb16,
        lvl_nodes, lvl_cnt, lvl_start, nlev, lvl_done, tree_done,
        Bbf, b_out, out);
}

// Round 11
// 541.843 us; speedup vs baseline: 1.2565x; 1.2565x over previous
//
#include <hip/hip_runtime.h>
#include <hip/hip_bf16.h>

typedef unsigned short u16;
typedef unsigned int u32;
typedef unsigned long long u64;
typedef __attribute__((ext_vector_type(8))) short short8;
typedef __attribute__((ext_vector_type(4))) float f32x4;

#define NB 32      // trees
#define NN 128     // nodes per tree
#define HH 300     // hidden
#define G4 1200    // 4*H
#define NV 32000   // vocab
#define INW 350    // RD+E
#define KP 320     // padded K; hb16 row stride

// scan: 32 trees x 15 slices, level-synchronous, MFMA MV
#define NSLICE 15
#define UPS 20            // units per slice -> 80 gate rows
#define NROWS 80
#define TPBS 320          // 5 waves; wave w owns gate-row tile w
#define GMAXN 16          // node batch per pass
#define LDW 328           // padded bf16 row stride (656 B, 16B-aligned)

#define A_LD(p)     __hip_atomic_load((p), __ATOMIC_RELAXED, __HIP_MEMORY_SCOPE_AGENT)
#define A_ST(p, v)  __hip_atomic_store((p), (v), __ATOMIC_RELAXED, __HIP_MEMORY_SCOPE_AGENT)
#define A_ADD(p, v) __hip_atomic_fetch_add((p), (v), __ATOMIC_RELAXED, __HIP_MEMORY_SCOPE_AGENT)

__device__ __forceinline__ float sigm(float x) { return 1.f / (1.f + __expf(-x)); }
__device__ __forceinline__ float tanh_f(float x) {
    float e = __expf(2.f * x);
    return 1.f - 2.f / (e + 1.f);
}
__device__ __forceinline__ u16 f2bf(float f) {
    __hip_bfloat16 b = __float2bfloat16(f);
    return *reinterpret_cast<u16*>(&b);
}

// hb16: [B][129][320] bf16, slot 0 = root h; lvl_done zeroed every launch
__global__ void k_init(const float* __restrict__ rh, u16* __restrict__ hb16,
                       int* __restrict__ lvl_done) {
    const int stride = gridDim.x * blockDim.x;
    const int idx = blockIdx.x * blockDim.x + threadIdx.x;
    for (int e = idx; e < NB * 129 * 20; e += stride) {
        int row = e / 20, c = 300 + (e - row * 20);
        hb16[(size_t)row * KP + c] = 0;
    }
    for (int e = idx; e < NB * HH; e += stride) {
        int b = e / HH, u = e - b * HH;
        hb16[(size_t)(b * 129) * KP + u] = f2bf(rh[e]);
    }
    for (int e = idx; e < NB * NN; e += stride) lvl_done[e] = 0;
}

// WihT [350][1200] f32; Wp16 [15][80][328] bf16:
//   slice s, row r (= g*20+ul), col k -> W_hh[g*300 + s*20 + ul][k] (0 for k>=300)
__global__ void k_pack(const float* __restrict__ W_ih, const float* __restrict__ W_hh,
                       float* __restrict__ WihT, u16* __restrict__ Wp16) {
    const int tot = INW * G4 + NSLICE * NROWS * LDW;
    for (int n = blockIdx.x * blockDim.x + threadIdx.x; n < tot; n += gridDim.x * blockDim.x) {
        if (n < INW * G4) {
            int c = n / G4, r = n - c * G4;
            WihT[n] = W_ih[r * INW + c];
        } else {
            int m = n - INW * G4;
            int s = m / (NROWS * LDW);
            int rem = m - s * (NROWS * LDW);
            int r = rem / LDW, k = rem - r * LDW;
            int g = r / UPS, ul = r - g * UPS;
            int grow = g * HH + s * UPS + ul;
            float v = (k < HH) ? W_hh[grow * HH + k] : 0.f;
            Wp16[m] = f2bf(v);
        }
    }
}

// xg[node][1200] = concat(rel_emb[rel], emb[word]) @ W_ih^T + b_ih
__global__ __launch_bounds__(256) void k_xg(const int* __restrict__ relations,
                                            const int* __restrict__ prev_words,
                                            const float* __restrict__ rel_emb,
                                            const float* __restrict__ emb,
                                            const float* __restrict__ WihT,
                                            const float* __restrict__ b_ih,
                                            float* __restrict__ xg) {
    __shared__ float xl[8][INW];
    __shared__ int rid[8], wid[8];
    const int tid = threadIdx.x;
    const int nb = blockIdx.x * 8;
    if (tid < 8) { rid[tid] = relations[nb + tid]; wid[tid] = prev_words[nb + tid]; }
    __syncthreads();
    for (int idx = tid; idx < 8 * INW; idx += 256) {
        int g = idx / INW, c = idx - g * INW;
        xl[g][c] = (c < 50) ? rel_emb[rid[g] * 50 + c] : emb[wid[g] * HH + (c - 50)];
    }
    __syncthreads();
    for (int k = 0; k < 5; ++k) {
        int r = k * 256 + tid;
        if (r >= G4) break;
        float acc[8] = {0.f, 0.f, 0.f, 0.f, 0.f, 0.f, 0.f, 0.f};
        for (int c = 0; c < INW; ++c) {
            float wv = WihT[(size_t)c * G4 + r];
#pragma unroll
            for (int g = 0; g < 8; ++g) acc[g] += wv * xl[g][c];
        }
        float bi = b_ih[r];
#pragma unroll
        for (int g = 0; g < 8; ++g) xg[(size_t)(nb + g) * G4 + r] = acc[g] + bi;
    }
}

// per-tree level schedule
__global__ void k_prep(const int* __restrict__ parents, int* __restrict__ lvl_nodes,
                       int* __restrict__ lvl_cnt, int* __restrict__ lvl_start,
                       int* __restrict__ nlev) {
    __shared__ int dep[NB][NN];
    __shared__ int cnt[NB][NN];
    __shared__ int st[NB][NN];
    const int t = threadIdx.x;
    if (t < NB) {
        for (int l = 0; l < NN; ++l) cnt[t][l] = 0;
        int md = 0;
        for (int i = 0; i < NN; ++i) {
            int p = parents[t * NN + i];
            int d = (p < 0) ? 0 : dep[t][p] + 1;
            dep[t][i] = d;
            cnt[t][d]++;
            md = max(md, d);
        }
        nlev[t] = md + 1;
        int run = 0;
        for (int l = 0; l < NN; ++l) {
            st[t][l] = run;
            lvl_start[t * NN + l] = run;
            lvl_cnt[t * NN + l] = cnt[t][l];
            run += cnt[t][l];
        }
        for (int i = 0; i < NN; ++i) {
            int d = dep[t][i];
            lvl_nodes[t * NN + st[t][d]] = i;
            st[t][d]++;
        }
    }
}

// Level-synchronous MFMA scan. Block (tree b, slice s). W slice bf16 in LDS
// (staged once); per pass: stage <=16 parent-h rows bf16 -> LDS, 5 waves do
// [16x16]x(K=320) MFMA vs W rows, gates->LDS, 160 threads run the cell (c in
// LDS, slice-local), publish h to hb16 as u32 bf16-pairs (agent-scope atomics,
// R6-R9-proven). Rendezvous per level via lvl_done counter.
__global__ __launch_bounds__(TPBS) void k_scan(const int* __restrict__ parents,
                                               const u16* __restrict__ Wp16,
                                               const float* __restrict__ xg,
                                               const float* __restrict__ b_hh,
                                               const float* __restrict__ rh,
                                               u16* __restrict__ hb16,
                                               const int* __restrict__ lvl_nodes,
                                               const int* __restrict__ lvl_cnt,
                                               const int* __restrict__ lvl_start,
                                               const int* __restrict__ nlev,
                                               int* __restrict__ lvl_done) {
    __shared__ __align__(16) u16 Wl[NROWS * LDW];     // 52480 B
    __shared__ __align__(16) u16 hs[GMAXN * LDW];     // 10496 B
    __shared__ __align__(16) float gates[GMAXN * 82]; // 5248 B
    __shared__ float c_lds[129 * UPS];                // 10320 B
    __shared__ int nid_s[GMAXN], par_s[GMAXN];

    const int t = threadIdx.x;
    const int b = blockIdx.x / NSLICE;
    const int s = blockIdx.x % NSLICE;
    const int lane = t & 63, wv = t >> 6;
    const int lrow = lane & 15, lk = lane >> 4;

    // stage W slice into LDS once (plain coalesced u64 copy)
    {
        const u64* src = (const u64*)(Wp16 + (size_t)s * NROWS * LDW);
        u64* dst = (u64*)Wl;
        for (int e = t; e < NROWS * LDW / 4; e += TPBS) dst[e] = src[e];
    }
    if (t < UPS) c_lds[t] = rh[b * HH + s * UPS + t];  // root c slice
    __syncthreads();

    const int nl = nlev[b];
    for (int l = 0; l < nl; ++l) {
        const int cnt = lvl_cnt[b * NN + l];
        const int start = lvl_start[b * NN + l];
        for (int off = 0; off < cnt; off += GMAXN) {
            const int gc = min(GMAXN, cnt - off);
            if (t < gc) {
                int i = lvl_nodes[b * NN + start + off + t];
                nid_s[t] = i;
                par_s[t] = parents[b * NN + i];
            }
            __syncthreads();
            // stage parent h rows (bf16, u64 agent loads; 80 u64 per row)
            for (int e = t; e < gc * 80; e += TPBS) {
                const int j = e / 80, q = e - j * 80;
                const u64* hrow = (const u64*)(hb16 +
                    (size_t)(b * 129 + par_s[j] + 1) * KP);
                *(u64*)&hs[j * LDW + q * 4] = A_LD(&hrow[q]);
            }
            __syncthreads();
            // MFMA: wave wv computes nodes x gate-rows [wv*16 .. wv*16+15]
            {
                f32x4 acc = {};
#pragma unroll
                for (int kk = 0; kk < KP; kk += 32) {
                    short8 av = *(const short8*)&hs[lrow * LDW + kk + lk * 8];
                    short8 bv = *(const short8*)&Wl[(wv * 16 + lrow) * LDW + kk + lk * 8];
                    acc = __builtin_amdgcn_mfma_f32_16x16x32_bf16(av, bv, acc, 0, 0, 0);
                }
#pragma unroll
                for (int r = 0; r < 4; ++r)
                    gates[(lk * 4 + r) * 82 + wv * 16 + lrow] = acc[r];
            }
            __syncthreads();
            // cell: thread t<160 -> (node j, unit pair up)
            if (t < 160) {
                const int j = t / 10, up = t - j * 10;
                if (j < gc) {
                    const int i = nid_s[j];
                    const int par = par_s[j];
                    const int ul0 = up * 2;
                    const float* gj = gates + j * 82;
                    const float* xgp = xg + (size_t)(b * NN + i) * G4 + s * UPS;
                    const float* bhp = b_hh + s * UPS;
                    float hv[2];
#pragma unroll
                    for (int un = 0; un < 2; ++un) {
                        const int ul = ul0 + un;
                        float gs[4];
#pragma unroll
                        for (int g = 0; g < 4; ++g)
                            gs[g] = gj[g * UPS + ul] + xgp[g * HH + ul] + bhp[g * HH + ul];
                        const float pc = c_lds[(par + 1) * UPS + ul];
                        const float cv = sigm(gs[1]) * pc + sigm(gs[0]) * tanh_f(gs[2]);
                        hv[un] = sigm(gs[3]) * tanh_f(cv);
                        c_lds[(i + 1) * UPS + ul] = cv;
                    }
                    const u32 hp = (u32)f2bf(hv[0]) | ((u32)f2bf(hv[1]) << 16);
                    A_ST((u32*)(hb16 + (size_t)(b * 129 + i + 1) * KP + s * UPS + ul0), hp);
                }
            }
            __syncthreads();  // drains h publishes (vmcnt0) + LDS reuse safety
        }
        if (l + 1 < nl) {  // rendezvous: all 15 slice-blocks of tree b finish level l
            if (t == 0) {
                int* dp = &lvl_done[b * NN + l];
                const int old = A_ADD(dp, 1);
                if (old != NSLICE - 1) {
                    while (A_LD(dp) < NSLICE) __builtin_amdgcn_s_sleep(1);
                }
            }
            __syncthreads();
        }
    }
}

// cast W_out -> bf16 [32000][320] (zero-padded K)
__global__ void k_cast_B(const float* __restrict__ W_out, u16* __restrict__ Bm) {
    for (int e = blockIdx.x * blockDim.x + threadIdx.x; e < NV * KP;
         e += gridDim.x * blockDim.x) {
        int v = e / KP, k = e - v * KP;
        float x = (k < HH) ? W_out[v * HH + k] : 0.f;
        Bm[e] = f2bf(x);
    }
}

// logits[4096][32000] = A(bf16, from hb16) @ B(bf16)^T + b_out, fp32 accum.
// 1D grid 8000, XCD-swizzled: each XCD owns a contiguous nblk range.
__global__ __launch_bounds__(256) void k_gemm(const u16* __restrict__ hb16,
                                              const u16* __restrict__ Bbf,
                                              const float* __restrict__ b_out,
                                              float* __restrict__ out) {
    __shared__ __align__(16) u16 As[128 * 40];
    __shared__ __align__(16) u16 Bs[128 * 40];
    const int tid = threadIdx.x;
    const int lane = tid & 63, wv = tid >> 6;
    const int wm = wv >> 1, wn = wv & 1;
    const int bid = blockIdx.x;                  // 8000 = 32 mblk x 250 nblk
    const int newbid = (bid & 7) * 1000 + (bid >> 3);
    const int mblk = newbid & 31, nblk = newbid >> 5;
    const u16* Ag = hb16 + ((size_t)mblk * 129 + 1) * KP;
    const u16* Bg = Bbf + (size_t)nblk * 128 * KP;
    f32x4 acc[4][4] = {};
    const int lrow = lane & 15, lseg = lane >> 4;
    for (int kk = 0; kk < KP; kk += 32) {
#pragma unroll
        for (int q = 0; q < 2; ++q) {
            int s = tid + q * 256;
            int r = s >> 2, seg = s & 3;
            *(uint4*)&As[r * 40 + seg * 8] = *(const uint4*)&Ag[r * KP + kk + seg * 8];
            *(uint4*)&Bs[r * 40 + seg * 8] = *(const uint4*)&Bg[r * KP + kk + seg * 8];
        }
        __syncthreads();
        short8 av[4], bv[4];
#pragma unroll
        for (int i = 0; i < 4; ++i) {
            av[i] = *(const short8*)&As[(wm * 64 + i * 16 + lrow) * 40 + lseg * 8];
            bv[i] = *(const short8*)&Bs[(wn * 64 + i * 16 + lrow) * 40 + lseg * 8];
        }
#pragma unroll
        for (int i = 0; i < 4; ++i)
#pragma unroll
            for (int j = 0; j < 4; ++j)
                acc[i][j] = __builtin_amdgcn_mfma_f32_16x16x32_bf16(av[i], bv[j], acc[i][j],
                                                                    0, 0, 0);
        __syncthreads();
    }
#pragma unroll
    for (int j = 0; j < 4; ++j) {
        int col = nblk * 128 + wn * 64 + j * 16 + lrow;
        float bo = b_out[col];
#pragma unroll
        for (int i = 0; i < 4; ++i) {
            int row0 = mblk * 128 + wm * 64 + i * 16 + lseg * 4;
#pragma unroll
            for (int q = 0; q < 4; ++q) {
                out[(size_t)(row0 + q) * NV + col] = acc[i][j][q] + bo;
            }
        }
    }
}

extern "C" void kernel_launch(void* const* d_in, const int* in_sizes, int n_in,
                              void* d_out, int out_size, void* d_ws, size_t ws_size,
                              hipStream_t stream) {
    const float* root_hidden = (const float*)d_in[0];
    const int* relations = (const int*)d_in[1];
    const int* prev_words = (const int*)d_in[2];
    const int* parents = (const int*)d_in[3];
    const float* emb = (const float*)d_in[4];
    const float* rel_emb = (const float*)d_in[5];
    const float* W_ih = (const float*)d_in[6];
    const float* W_hh = (const float*)d_in[7];
    const float* b_ih = (const float*)d_in[8];
    const float* b_hh = (const float*)d_in[9];
    const float* W_out = (const float*)d_in[10];
    const float* b_out = (const float*)d_in[11];
    float* out = (float*)d_out;

    float* WihT = (float*)d_ws;                    // 420000 f32
    float* xg = WihT + 420000;                     // 4915200 f32
    u16* Wp16 = (u16*)(xg + 4915200);              // 15*80*328 = 393600 u16
    u16* hb16 = Wp16 + 393600;                     // 1320960 u16
    u16* Bbf = hb16 + 1320960;                     // 10240000 u16
    int* lvl_nodes = (int*)(Bbf + 10240000);       // 4096 i32
    int* lvl_cnt = lvl_nodes + 4096;               // 4096 i32
    int* lvl_start = lvl_cnt + 4096;               // 4096 i32
    int* nlev = lvl_start + 4096;                  // 32 i32 (+pad)
    int* lvl_done = nlev + 64;                     // 4096 i32

    k_init<<<128, 256, 0, stream>>>(root_hidden, hb16, lvl_done);
    k_pack<<<2048, 256, 0, stream>>>(W_ih, W_hh, WihT, Wp16);
    k_xg<<<NB * NN / 8, 256, 0, stream>>>(relations, prev_words, rel_emb, emb, WihT, b_ih, xg);
    k_prep<<<1, 64, 0, stream>>>(parents, lvl_nodes, lvl_cnt, lvl_start, nlev);

    k_scan<<<dim3(NB * NSLICE), dim3(TPBS), 0, stream>>>(
        parents, Wp16, xg, b_hh, root_hidden, hb16,
        lvl_nodes, lvl_cnt, lvl_start, nlev, lvl_done);

    k_cast_B<<<4096, 256, 0, stream>>>(W_out, Bbf);
    k_gemm<<<dim3(8000), 256, 0, stream>>>(hb16, Bbf, b_out, out);
}

// Round 12
// 341.721 us; speedup vs baseline: 1.9923x; 1.5856x over previous
//
#include <hip/hip_runtime.h>
#include <hip/hip_bf16.h>

typedef unsigned short u16;
typedef unsigned int u32;
typedef unsigned long long u64;
typedef __attribute__((ext_vector_type(8))) short short8;
typedef __attribute__((ext_vector_type(4))) float f32x4;

#define NB 32      // trees
#define NN 128     // nodes per tree
#define HH 300     // hidden
#define NV 32000   // vocab
#define KP 320     // padded K; hb16 row stride
#define KX 352     // padded RD+E (350 -> 352)
#define XGS 1280   // xg row stride (1200 -> 1280)

// scan: 32 trees x 15 slices, level-synchronous, MFMA MV
#define NSLICE 15
#define UPS 20            // units per slice -> 80 gate rows
#define NROWS 80
#define TPBS 320          // 5 waves; wave w owns gate-row tile w
#define GMAXN 16          // node batch per pass
#define LDW 328           // padded bf16 row stride

#define A_LD(p)     __hip_atomic_load((p), __ATOMIC_RELAXED, __HIP_MEMORY_SCOPE_AGENT)
#define A_ST(p, v)  __hip_atomic_store((p), (v), __ATOMIC_RELAXED, __HIP_MEMORY_SCOPE_AGENT)
#define A_ADD(p, v) __hip_atomic_fetch_add((p), (v), __ATOMIC_RELAXED, __HIP_MEMORY_SCOPE_AGENT)

__device__ __forceinline__ float sigm(float x) { return 1.f / (1.f + __expf(-x)); }
__device__ __forceinline__ float tanh_f(float x) {
    float e = __expf(2.f * x);
    return 1.f - 2.f / (e + 1.f);
}
__device__ __forceinline__ u16 f2bf(float f) {
    __hip_bfloat16 b = __float2bfloat16(f);
    return *reinterpret_cast<u16*>(&b);
}

// hb16: [B][129][320] bf16, slot 0 = root h; lvl_done zeroed every launch
__global__ void k_init(const float* __restrict__ rh, u16* __restrict__ hb16,
                       int* __restrict__ lvl_done) {
    const int stride = gridDim.x * blockDim.x;
    const int idx = blockIdx.x * blockDim.x + threadIdx.x;
    for (int e = idx; e < NB * 129 * 20; e += stride) {
        int row = e / 20, c = 300 + (e - row * 20);
        hb16[(size_t)row * KP + c] = 0;
    }
    for (int e = idx; e < NB * HH; e += stride) {
        int b = e / HH, u = e - b * HH;
        hb16[(size_t)(b * 129) * KP + u] = f2bf(rh[e]);
    }
    for (int e = idx; e < NB * NN; e += stride) lvl_done[e] = 0;
}

// Wihp [1280][352] bf16 (= W_ih zero-padded, row=gate-row, col=k);
// Wp16 [15][80][328] bf16 (scan W_hh slices)
__global__ void k_pack(const float* __restrict__ W_ih, const float* __restrict__ W_hh,
                       u16* __restrict__ Wihp, u16* __restrict__ Wp16) {
    const int tot = 1280 * KX + NSLICE * NROWS * LDW;
    for (int n = blockIdx.x * blockDim.x + threadIdx.x; n < tot; n += gridDim.x * blockDim.x) {
        if (n < 1280 * KX) {
            int r = n / KX, k = n - r * KX;
            float v = (r < 1200 && k < 350) ? W_ih[r * 350 + k] : 0.f;
            Wihp[n] = f2bf(v);
        } else {
            int m = n - 1280 * KX;
            int s = m / (NROWS * LDW);
            int rem = m - s * (NROWS * LDW);
            int r = rem / LDW, k = rem - r * LDW;
            int g = r / UPS, ul = r - g * UPS;
            int grow = g * HH + s * UPS + ul;
            float v = (k < HH) ? W_hh[grow * HH + k] : 0.f;
            Wp16[m] = f2bf(v);
        }
    }
}

// Xbf [4096][352] bf16 = concat(rel_emb[rel], emb[word], 0-pad)
__global__ void k_gatherX(const int* __restrict__ relations, const int* __restrict__ prev_words,
                          const float* __restrict__ rel_emb, const float* __restrict__ emb,
                          u16* __restrict__ X) {
    for (int e = blockIdx.x * blockDim.x + threadIdx.x; e < NB * NN * KX;
         e += gridDim.x * blockDim.x) {
        int node = e / KX, c = e - node * KX;
        float v = 0.f;
        if (c < 50) v = rel_emb[relations[node] * 50 + c];
        else if (c < 350) v = emb[(size_t)prev_words[node] * 300 + (c - 50)];
        X[e] = f2bf(v);
    }
}

// per-tree level schedule
__global__ void k_prep(const int* __restrict__ parents, int* __restrict__ lvl_nodes,
                       int* __restrict__ lvl_cnt, int* __restrict__ lvl_start,
                       int* __restrict__ nlev) {
    __shared__ int dep[NB][NN];
    __shared__ int cnt[NB][NN];
    __shared__ int st[NB][NN];
    const int t = threadIdx.x;
    if (t < NB) {
        for (int l = 0; l < NN; ++l) cnt[t][l] = 0;
        int md = 0;
        for (int i = 0; i < NN; ++i) {
            int p = parents[t * NN + i];
            int d = (p < 0) ? 0 : dep[t][p] + 1;
            dep[t][i] = d;
            cnt[t][d]++;
            md = max(md, d);
        }
        nlev[t] = md + 1;
        int run = 0;
        for (int l = 0; l < NN; ++l) {
            st[t][l] = run;
            lvl_start[t * NN + l] = run;
            lvl_cnt[t * NN + l] = cnt[t][l];
            run += cnt[t][l];
        }
        for (int i = 0; i < NN; ++i) {
            int d = dep[t][i];
            lvl_nodes[t * NN + st[t][d]] = i;
            st[t][d]++;
        }
    }
}

// xg[4096][1280] = X(bf16) @ Wihp(bf16)^T + b_ih, fp32. 128x128 tiles, swapped-MFMA
// epilogue (lane holds 1 row x 4 consecutive cols -> f32x4 stores).
__global__ __launch_bounds__(256) void k_xgemm(const u16* __restrict__ Xbf,
                                               const u16* __restrict__ Wihp,
                                               const float* __restrict__ b_ih,
                                               float* __restrict__ xg) {
    __shared__ __align__(16) u16 As[128 * 40];
    __shared__ __align__(16) u16 Bs[128 * 40];
    const int tid = threadIdx.x;
    const int lane = tid & 63, wv = tid >> 6;
    const int wm = wv >> 1, wn = wv & 1;
    const int mblk = blockIdx.x, nblk = blockIdx.y;
    const u16* Ag = Xbf + (size_t)mblk * 128 * KX;
    const u16* Bg = Wihp + (size_t)nblk * 128 * KX;
    f32x4 acc[4][4] = {};
    const int lrow = lane & 15, lseg = lane >> 4;
    for (int kk = 0; kk < KX; kk += 32) {
#pragma unroll
        for (int q = 0; q < 2; ++q) {
            int s = tid + q * 256;
            int r = s >> 2, seg = s & 3;
            *(uint4*)&As[r * 40 + seg * 8] = *(const uint4*)&Ag[(size_t)r * KX + kk + seg * 8];
            *(uint4*)&Bs[r * 40 + seg * 8] = *(const uint4*)&Bg[(size_t)r * KX + kk + seg * 8];
        }
        __syncthreads();
        short8 av[4], bv[4];
#pragma unroll
        for (int i = 0; i < 4; ++i) {
            av[i] = *(const short8*)&As[(wm * 64 + i * 16 + lrow) * 40 + lseg * 8];
            bv[i] = *(const short8*)&Bs[(wn * 64 + i * 16 + lrow) * 40 + lseg * 8];
        }
#pragma unroll
        for (int i = 0; i < 4; ++i)
#pragma unroll
            for (int j = 0; j < 4; ++j)
                acc[i][j] = __builtin_amdgcn_mfma_f32_16x16x32_bf16(bv[j], av[i], acc[i][j],
                                                                    0, 0, 0);
        __syncthreads();
    }
    // swapped layout: row = m (lane&15), cols = n base + (lane>>4)*4 + reg (consecutive)
#pragma unroll
    for (int i = 0; i < 4; ++i) {
        const int row = mblk * 128 + wm * 64 + i * 16 + lrow;
        float* orow = xg + (size_t)row * XGS;
#pragma unroll
        for (int j = 0; j < 4; ++j) {
            const int col = nblk * 128 + wn * 64 + j * 16 + lseg * 4;
            f32x4 v = acc[i][j];
            if (col < 1200) {
                f32x4 bo = *(const f32x4*)&b_ih[col];
                v[0] += bo[0]; v[1] += bo[1]; v[2] += bo[2]; v[3] += bo[3];
            }
            *(f32x4*)&orow[col] = v;
        }
    }
}

// Level-synchronous MFMA scan (R11 structure, proven). Only change: xg stride 1280.
__global__ __launch_bounds__(TPBS) void k_scan(const int* __restrict__ parents,
                                               const u16* __restrict__ Wp16,
                                               const float* __restrict__ xg,
                                               const float* __restrict__ b_hh,
                                               const float* __restrict__ rh,
                                               u16* __restrict__ hb16,
                                               const int* __restrict__ lvl_nodes,
                                               const int* __restrict__ lvl_cnt,
                                               const int* __restrict__ lvl_start,
                                               const int* __restrict__ nlev,
                                               int* __restrict__ lvl_done) {
    __shared__ __align__(16) u16 Wl[NROWS * LDW];     // 52480 B
    __shared__ __align__(16) u16 hs[GMAXN * LDW];     // 10496 B
    __shared__ __align__(16) float gates[GMAXN * 82]; // 5248 B
    __shared__ float c_lds[129 * UPS];                // 10320 B
    __shared__ int nid_s[GMAXN], par_s[GMAXN];

    const int t = threadIdx.x;
    const int b = blockIdx.x / NSLICE;
    const int s = blockIdx.x % NSLICE;
    const int lane = t & 63, wv = t >> 6;
    const int lrow = lane & 15, lk = lane >> 4;

    {
        const u64* src = (const u64*)(Wp16 + (size_t)s * NROWS * LDW);
        u64* dst = (u64*)Wl;
        for (int e = t; e < NROWS * LDW / 4; e += TPBS) dst[e] = src[e];
    }
    if (t < UPS) c_lds[t] = rh[b * HH + s * UPS + t];
    __syncthreads();

    const int nl = nlev[b];
    for (int l = 0; l < nl; ++l) {
        const int cnt = lvl_cnt[b * NN + l];
        const int start = lvl_start[b * NN + l];
        for (int off = 0; off < cnt; off += GMAXN) {
            const int gc = min(GMAXN, cnt - off);
            if (t < gc) {
                int i = lvl_nodes[b * NN + start + off + t];
                nid_s[t] = i;
                par_s[t] = parents[b * NN + i];
            }
            __syncthreads();
            for (int e = t; e < gc * 80; e += TPBS) {
                const int j = e / 80, q = e - j * 80;
                const u64* hrow = (const u64*)(hb16 +
                    (size_t)(b * 129 + par_s[j] + 1) * KP);
                *(u64*)&hs[j * LDW + q * 4] = A_LD(&hrow[q]);
            }
            __syncthreads();
            {
                f32x4 acc = {};
#pragma unroll
                for (int kk = 0; kk < KP; kk += 32) {
                    short8 av = *(const short8*)&hs[lrow * LDW + kk + lk * 8];
                    short8 bv = *(const short8*)&Wl[(wv * 16 + lrow) * LDW + kk + lk * 8];
                    acc = __builtin_amdgcn_mfma_f32_16x16x32_bf16(av, bv, acc, 0, 0, 0);
                }
#pragma unroll
                for (int r = 0; r < 4; ++r)
                    gates[(lk * 4 + r) * 82 + wv * 16 + lrow] = acc[r];
            }
            __syncthreads();
            if (t < 160) {
                const int j = t / 10, up = t - j * 10;
                if (j < gc) {
                    const int i = nid_s[j];
                    const int par = par_s[j];
                    const int ul0 = up * 2;
                    const float* gj = gates + j * 82;
                    const float* xgp = xg + (size_t)(b * NN + i) * XGS + s * UPS;
                    const float* bhp = b_hh + s * UPS;
                    float hv[2];
#pragma unroll
                    for (int un = 0; un < 2; ++un) {
                        const int ul = ul0 + un;
                        float gs[4];
#pragma unroll
                        for (int g = 0; g < 4; ++g)
                            gs[g] = gj[g * UPS + ul] + xgp[g * HH + ul] + bhp[g * HH + ul];
                        const float pc = c_lds[(par + 1) * UPS + ul];
                        const float cv = sigm(gs[1]) * pc + sigm(gs[0]) * tanh_f(gs[2]);
                        hv[un] = sigm(gs[3]) * tanh_f(cv);
                        c_lds[(i + 1) * UPS + ul] = cv;
                    }
                    const u32 hp = (u32)f2bf(hv[0]) | ((u32)f2bf(hv[1]) << 16);
                    A_ST((u32*)(hb16 + (size_t)(b * 129 + i + 1) * KP + s * UPS + ul0), hp);
                }
            }
            __syncthreads();
        }
        if (l + 1 < nl) {
            if (t == 0) {
                int* dp = &lvl_done[b * NN + l];
                const int old = A_ADD(dp, 1);
                if (old != NSLICE - 1) {
                    while (A_LD(dp) < NSLICE) __builtin_amdgcn_s_sleep(1);
                }
            }
            __syncthreads();
        }
    }
}

// cast W_out -> bf16 [32000][320] (zero-padded K)
__global__ void k_cast_B(const float* __restrict__ W_out, u16* __restrict__ Bm) {
    for (int e = blockIdx.x * blockDim.x + threadIdx.x; e < NV * KP;
         e += gridDim.x * blockDim.x) {
        int v = e / KP, k = e - v * KP;
        float x = (k < HH) ? W_out[v * HH + k] : 0.f;
        Bm[e] = f2bf(x);
    }
}

// logits[4096][32000] = A(bf16, from hb16) @ B(bf16)^T + b_out, fp32 accum.
// Swapped-MFMA epilogue -> f32x4 nontemporal stores; XCD-swizzled 1D grid.
__global__ __launch_bounds__(256) void k_gemm(const u16* __restrict__ hb16,
                                              const u16* __restrict__ Bbf,
                                              const float* __restrict__ b_out,
                                              float* __restrict__ out) {
    __shared__ __align__(16) u16 As[128 * 40];
    __shared__ __align__(16) u16 Bs[128 * 40];
    const int tid = threadIdx.x;
    const int lane = tid & 63, wv = tid >> 6;
    const int wm = wv >> 1, wn = wv & 1;
    const int bid = blockIdx.x;                  // 8000 = 32 mblk x 250 nblk
    const int newbid = (bid & 7) * 1000 + (bid >> 3);
    const int mblk = newbid & 31, nblk = newbid >> 5;
    const u16* Ag = hb16 + ((size_t)mblk * 129 + 1) * KP;
    const u16* Bg = Bbf + (size_t)nblk * 128 * KP;
    f32x4 acc[4][4] = {};
    const int lrow = lane & 15, lseg = lane >> 4;
    for (int kk = 0; kk < KP; kk += 32) {
#pragma unroll
        for (int q = 0; q < 2; ++q) {
            int s = tid + q * 256;
            int r = s >> 2, seg = s & 3;
            *(uint4*)&As[r * 40 + seg * 8] = *(const uint4*)&Ag[r * KP + kk + seg * 8];
            *(uint4*)&Bs[r * 40 + seg * 8] = *(const uint4*)&Bg[r * KP + kk + seg * 8];
        }
        __syncthreads();
        short8 av[4], bv[4];
#pragma unroll
        for (int i = 0; i < 4; ++i) {
            av[i] = *(const short8*)&As[(wm * 64 + i * 16 + lrow) * 40 + lseg * 8];
            bv[i] = *(const short8*)&Bs[(wn * 64 + i * 16 + lrow) * 40 + lseg * 8];
        }
#pragma unroll
        for (int i = 0; i < 4; ++i)
#pragma unroll
            for (int j = 0; j < 4; ++j)
                acc[i][j] = __builtin_amdgcn_mfma_f32_16x16x32_bf16(bv[j], av[i], acc[i][j],
                                                                    0, 0, 0);
        __syncthreads();
    }
    // swapped layout: row = m (lane&15), cols = n base + (lane>>4)*4 + reg
#pragma unroll
    for (int i = 0; i < 4; ++i) {
        const int row = mblk * 128 + wm * 64 + i * 16 + lrow;
        float* orow = out + (size_t)row * NV;
#pragma unroll
        for (int j = 0; j < 4; ++j) {
            const int col = nblk * 128 + wn * 64 + j * 16 + lseg * 4;
            f32x4 v = acc[i][j];
            f32x4 bo = *(const f32x4*)&b_out[col];
            v[0] += bo[0]; v[1] += bo[1]; v[2] += bo[2]; v[3] += bo[3];
            __builtin_nontemporal_store(v, (f32x4*)&orow[col]);
        }
    }
}

extern "C" void kernel_launch(void* const* d_in, const int* in_sizes, int n_in,
                              void* d_out, int out_size, void* d_ws, size_t ws_size,
                              hipStream_t stream) {
    const float* root_hidden = (const float*)d_in[0];
    const int* relations = (const int*)d_in[1];
    const int* prev_words = (const int*)d_in[2];
    const int* parents = (const int*)d_in[3];
    const float* emb = (const float*)d_in[4];
    const float* rel_emb = (const float*)d_in[5];
    const float* W_ih = (const float*)d_in[6];
    const float* W_hh = (const float*)d_in[7];
    const float* b_ih = (const float*)d_in[8];
    const float* b_hh = (const float*)d_in[9];
    const float* W_out = (const float*)d_in[10];
    const float* b_out = (const float*)d_in[11];
    float* out = (float*)d_out;

    float* xg = (float*)d_ws;                      // 4096*1280 f32
    u16* Xbf = (u16*)(xg + 4096 * XGS);            // 4096*352 u16
    u16* Wihp = Xbf + 4096 * KX;                   // 1280*352 u16
    u16* Wp16 = Wihp + 1280 * KX;                  // 15*80*328 u16
    u16* hb16 = Wp16 + NSLICE * NROWS * LDW;       // 1320960 u16
    u16* Bbf = hb16 + 1320960;                     // 10240000 u16
    int* lvl_nodes = (int*)(Bbf + 10240000);       // 4096 i32
    int* lvl_cnt = lvl_nodes + 4096;               // 4096 i32
    int* lvl_start = lvl_cnt + 4096;               // 4096 i32
    int* nlev = lvl_start + 4096;                  // 32 i32 (+pad)
    int* lvl_done = nlev + 64;                     // 4096 i32

    k_init<<<128, 256, 0, stream>>>(root_hidden, hb16, lvl_done);
    k_pack<<<1024, 256, 0, stream>>>(W_ih, W_hh, Wihp, Wp16);
    k_gatherX<<<1024, 256, 0, stream>>>(relations, prev_words, rel_emb, emb, Xbf);
    k_prep<<<1, 64, 0, stream>>>(parents, lvl_nodes, lvl_cnt, lvl_start, nlev);

    k_xgemm<<<dim3(32, 10), 256, 0, stream>>>(Xbf, Wihp, b_ih, xg);

    k_scan<<<dim3(NB * NSLICE), dim3(TPBS), 0, stream>>>(
        parents, Wp16, xg, b_hh, root_hidden, hb16,
        lvl_nodes, lvl_cnt, lvl_start, nlev, lvl_done);

    k_cast_B<<<4096, 256, 0, stream>>>(W_out, Bbf);
    k_gemm<<<dim3(8000), 256, 0, stream>>>(hb16, Bbf, b_out, out);
}